// Round 1
// 358.425 us; speedup vs baseline: 1.0691x; 1.0691x over previous
//
#include <hip/hip_runtime.h>
#include <hip/hip_bf16.h>

// LSTMFeatureExtractor: 2-layer LSTM (H=64, IN=1, B=2048, T=512) + FC(64->32)+ReLU
// R7 = kill the 4x MFMA M-redundancy. R6 counters: MfmaUtil 51% at 1711 cy/step
// = ~870 cy/step/SIMD of MFMA issue (48 MFMAs x ~18.5 cy), i.e. the MFMA pipe
// issue rate dominates -- and 3/4 of every MFMA's M-rows were replicated waste.
// Fix: MB=8 (2x replication only), 256 blocks x 512 threads (1 block/CU,
// 2 waves/SIMD), wave-specialized: waves 0-3 do layer0 (8 MFMA), waves 4-7 do
// layer1 (16 MFMA, independent accA/accB 2-chains). SIMD s gets waves s and
// s+4 -> one L0 + one L1 wave per SIMD = structural antiphase (replaces
// s_sleep). Per-SIMD MFMA issue: 864 -> 444 cy/step; VALU unchanged.

#define HID 64
#define TSTEPS 512
#define MB 8
#define RS 80   // f16 row stride: 160B = 40 words = 8 mod 32 -> benign

typedef _Float16 f16x8 __attribute__((ext_vector_type(8)));
typedef float f32x4 __attribute__((ext_vector_type(4)));

#define KSIG (-1.44269504089f)   // -log2(e)
#define KTANH (2.88539008178f)   // 2*log2(e)

__device__ __forceinline__ float fsig(float x) {
    return __builtin_amdgcn_rcpf(1.f + __builtin_amdgcn_exp2f(KSIG * x));
}
__device__ __forceinline__ float ftanh(float x) {
    return 1.f - 2.f * __builtin_amdgcn_rcpf(1.f + __builtin_amdgcn_exp2f(KTANH * x));
}

__global__ __launch_bounds__(512, 1) void lstm_feat_kernel(
    const float* __restrict__ x,
    const float* __restrict__ Wih0, const float* __restrict__ Whh0,
    const float* __restrict__ bih0, const float* __restrict__ bhh0,
    const float* __restrict__ Wih1, const float* __restrict__ Whh1,
    const float* __restrict__ bih1, const float* __restrict__ bhh1,
    const float* __restrict__ fcW, const float* __restrict__ fcb,
    float* __restrict__ out)
{
    __shared__ float x_lds[TSTEPS * MB];                    // 16 KB
    __shared__ __align__(16) _Float16 h0_lds[2][MB * RS];   // 2x1280 B
    __shared__ __align__(16) _Float16 h1_lds[2][MB * RS];
    __shared__ float h1f32[MB * HID];                       // 2 KB
    __shared__ float fcw_lds[HID * 32];                     // transposed [k][o], 8 KB
    __shared__ float fcb_lds[32];

    const int tid  = threadIdx.x;
    const int wave = tid >> 6;
    const int lane = tid & 63;
    const int nq   = lane & 15;
    const int quad = lane >> 4;
    const int bbase = blockIdx.x * MB;
    const bool isL1 = (wave >= 4);     // waves 0-3: layer0, waves 4-7: layer1
    const int ug = wave & 3;           // unit group (16 units)
    const int u  = ug * 16 + nq;       // hidden unit owned by this lane

    // ---- one-time staging ----
    for (int i = tid; i < TSTEPS * MB; i += 512) {
        int r = i >> 9, t = i & (TSTEPS - 1);
        x_lds[t * MB + r] = x[(bbase + r) * TSTEPS + t];    // coalesced in t
    }
    for (int i = tid; i < 32 * HID; i += 512) {
        int o = i >> 6, kk = i & 63;
        fcw_lds[kk * 32 + o] = fcW[i];                      // store transposed
    }
    if (tid < 32) fcb_lds[tid] = fcb[tid];
    for (int i = tid; i < 2 * MB * RS; i += 512) {
        ((_Float16*)h0_lds)[i] = (_Float16)0.f;             // H0[0]=0 (both bufs)
        ((_Float16*)h1_lds)[i] = (_Float16)0.f;             // H1[0]=0 (both bufs)
    }

    // ---- per-lane weight fragments (B operand: lane holds W[n][k0..k0+8)) ----
    // L0 waves: wA = Whh0 (wB = dup, unused). L1 waves: wA = Wih1, wB = Whh1.
    f16x8 wA[4][2], wB[4][2];
    float bA[4], wx0[4];
    {
        const float* Wa = isL1 ? Wih1 : Whh0;
        const float* Wb = isL1 ? Whh1 : Whh0;
        const float* bi = isL1 ? bih1 : bih0;
        const float* bh = isL1 ? bhh1 : bhh0;
        #pragma unroll
        for (int g = 0; g < 4; ++g) {
            const int n = g * 64 + u;
            bA[g]  = bi[n] + bh[n];
            wx0[g] = Wih0[n];          // IN==1 (only used by L0 waves)
            #pragma unroll
            for (int ks = 0; ks < 2; ++ks) {
                const int k0 = quad * 8 + ks * 32;
                f16x8 a, b;
                #pragma unroll
                for (int j = 0; j < 8; ++j) {
                    a[j] = (_Float16)Wa[n * HID + k0 + j];
                    b[j] = (_Float16)Wb[n * HID + k0 + j];
                }
                wA[g][ks] = a; wB[g][ks] = b;
            }
        }
    }

    const f32x4 zero4 = {0.f, 0.f, 0.f, 0.f};
    // A row m carries h[m>>1]: lane reads A-row nq -> h row nq>>1.
    // D row quad*4+reg -> batch (quad*4+reg)>>1: regs {0,1}->b0, {2,3}->b0+1.
    const int arow = (nq >> 1) * RS + quad * 8;
    const int b0 = quad * 2;           // this lane's first batch row
    float c0 = 0.f, c1 = 0.f;          // cell states for batches b0, b0+1

    __syncthreads();

    // ---- skewed recurrence: iter k makes H0[k+1] (x[k],H0[k]) and H1[k]
    //      (H0[k],H1[k-1]); single barrier; wave-specialized ----
    int p = 0;
    for (int k = 0; k < TSTEPS; ++k) {
        const int q = p ^ 1;
        if (!isL1) {
            // ---- layer 0: 8 MFMA (4 independent 2-chains) ----
            f16x8 a0[2];
            a0[0] = *(const f16x8*)&h0_lds[p][arow];
            a0[1] = *(const f16x8*)&h0_lds[p][arow + 32];
            const float2 xq = *(const float2*)&x_lds[k * MB + b0];
            f32x4 acc[4];
            #pragma unroll
            for (int g = 0; g < 4; ++g)
                acc[g] = __builtin_amdgcn_mfma_f32_16x16x32_f16(a0[0], wA[g][0], zero4, 0, 0, 0);
            #pragma unroll
            for (int g = 0; g < 4; ++g)
                acc[g] = __builtin_amdgcn_mfma_f32_16x16x32_f16(a0[1], wA[g][1], acc[g], 0, 0, 0);
            {   // batch b0 (element 0)
                const float pi = acc[0][0] + fmaf(xq.x, wx0[0], bA[0]);
                const float pf = acc[1][0] + fmaf(xq.x, wx0[1], bA[1]);
                const float pg = acc[2][0] + fmaf(xq.x, wx0[2], bA[2]);
                const float po = acc[3][0] + fmaf(xq.x, wx0[3], bA[3]);
                const float iv = fsig(pi), fv = fsig(pf), gv = ftanh(pg), ov = fsig(po);
                c0 = fv * c0 + iv * gv;
                h0_lds[q][b0 * RS + u] = (_Float16)(ov * ftanh(c0));
            }
            {   // batch b0+1 (element 2)
                const float pi = acc[0][2] + fmaf(xq.y, wx0[0], bA[0]);
                const float pf = acc[1][2] + fmaf(xq.y, wx0[1], bA[1]);
                const float pg = acc[2][2] + fmaf(xq.y, wx0[2], bA[2]);
                const float po = acc[3][2] + fmaf(xq.y, wx0[3], bA[3]);
                const float iv = fsig(pi), fv = fsig(pf), gv = ftanh(pg), ov = fsig(po);
                c1 = fv * c1 + iv * gv;
                h0_lds[q][(b0 + 1) * RS + u] = (_Float16)(ov * ftanh(c1));
            }
        } else {
            // ---- layer 1: 16 MFMA (8 independent 2-chains, K-major) ----
            f16x8 a0[2], a1[2];
            a0[0] = *(const f16x8*)&h0_lds[p][arow];
            a0[1] = *(const f16x8*)&h0_lds[p][arow + 32];
            a1[0] = *(const f16x8*)&h1_lds[p][arow];
            a1[1] = *(const f16x8*)&h1_lds[p][arow + 32];
            f32x4 accA[4], accB[4];
            #pragma unroll
            for (int g = 0; g < 4; ++g)
                accA[g] = __builtin_amdgcn_mfma_f32_16x16x32_f16(a0[0], wA[g][0], zero4, 0, 0, 0);
            #pragma unroll
            for (int g = 0; g < 4; ++g)
                accB[g] = __builtin_amdgcn_mfma_f32_16x16x32_f16(a1[0], wB[g][0], zero4, 0, 0, 0);
            #pragma unroll
            for (int g = 0; g < 4; ++g)
                accA[g] = __builtin_amdgcn_mfma_f32_16x16x32_f16(a0[1], wA[g][1], accA[g], 0, 0, 0);
            #pragma unroll
            for (int g = 0; g < 4; ++g)
                accB[g] = __builtin_amdgcn_mfma_f32_16x16x32_f16(a1[1], wB[g][1], accB[g], 0, 0, 0);
            if (k > 0) {   // H1[0] must stay 0 (buffers pre-zeroed)
                {   // batch b0 (element 0)
                    const float pi = accA[0][0] + accB[0][0] + bA[0];
                    const float pf = accA[1][0] + accB[1][0] + bA[1];
                    const float pg = accA[2][0] + accB[2][0] + bA[2];
                    const float po = accA[3][0] + accB[3][0] + bA[3];
                    const float iv = fsig(pi), fv = fsig(pf), gv = ftanh(pg), ov = fsig(po);
                    c0 = fv * c0 + iv * gv;
                    h1_lds[q][b0 * RS + u] = (_Float16)(ov * ftanh(c0));
                }
                {   // batch b0+1 (element 2)
                    const float pi = accA[0][2] + accB[0][2] + bA[0];
                    const float pf = accA[1][2] + accB[1][2] + bA[1];
                    const float pg = accA[2][2] + accB[2][2] + bA[2];
                    const float po = accA[3][2] + accB[3][2] + bA[3];
                    const float iv = fsig(pi), fv = fsig(pf), gv = ftanh(pg), ov = fsig(po);
                    c1 = fv * c1 + iv * gv;
                    h1_lds[q][(b0 + 1) * RS + u] = (_Float16)(ov * ftanh(c1));
                }
            }
        }
        p = q;
        __syncthreads();
    }

    // ---- peeled final layer-1 step: H1[512] from H0[512], H1[511] ----
    if (isL1) {
        f16x8 a0[2], a1[2];
        a0[0] = *(const f16x8*)&h0_lds[p][arow];
        a0[1] = *(const f16x8*)&h0_lds[p][arow + 32];
        a1[0] = *(const f16x8*)&h1_lds[p][arow];
        a1[1] = *(const f16x8*)&h1_lds[p][arow + 32];
        f32x4 accA[4], accB[4];
        #pragma unroll
        for (int g = 0; g < 4; ++g)
            accA[g] = __builtin_amdgcn_mfma_f32_16x16x32_f16(a0[0], wA[g][0], zero4, 0, 0, 0);
        #pragma unroll
        for (int g = 0; g < 4; ++g)
            accB[g] = __builtin_amdgcn_mfma_f32_16x16x32_f16(a1[0], wB[g][0], zero4, 0, 0, 0);
        #pragma unroll
        for (int g = 0; g < 4; ++g)
            accA[g] = __builtin_amdgcn_mfma_f32_16x16x32_f16(a0[1], wA[g][1], accA[g], 0, 0, 0);
        #pragma unroll
        for (int g = 0; g < 4; ++g)
            accB[g] = __builtin_amdgcn_mfma_f32_16x16x32_f16(a1[1], wB[g][1], accB[g], 0, 0, 0);
        {   // batch b0
            const float pi = accA[0][0] + accB[0][0] + bA[0];
            const float pf = accA[1][0] + accB[1][0] + bA[1];
            const float pg = accA[2][0] + accB[2][0] + bA[2];
            const float po = accA[3][0] + accB[3][0] + bA[3];
            const float iv = fsig(pi), fv = fsig(pf), gv = ftanh(pg), ov = fsig(po);
            c0 = fv * c0 + iv * gv;
            h1f32[b0 * HID + u] = ov * ftanh(c0);
        }
        {   // batch b0+1
            const float pi = accA[0][2] + accB[0][2] + bA[0];
            const float pf = accA[1][2] + accB[1][2] + bA[1];
            const float pg = accA[2][2] + accB[2][2] + bA[2];
            const float po = accA[3][2] + accB[3][2] + bA[3];
            const float iv = fsig(pi), fv = fsig(pf), gv = ftanh(pg), ov = fsig(po);
            c1 = fv * c1 + iv * gv;
            h1f32[(b0 + 1) * HID + u] = ov * ftanh(c1);
        }
    }
    __syncthreads();

    // ---- epilogue: features = relu(H1[512] @ fcW^T + fcb) ----
    if (tid < MB * 32) {
        const int o  = tid & 31;
        const int rr = tid >> 5;
        float acc = fcb_lds[o];
        #pragma unroll 8
        for (int kk = 0; kk < HID; ++kk)
            acc += h1f32[rr * HID + kk] * fcw_lds[kk * 32 + o];   // conflict-free
        out[(bbase + rr) * 32 + o] = fmaxf(acc, 0.f);
    }
}

extern "C" void kernel_launch(void* const* d_in, const int* in_sizes, int n_in,
                              void* d_out, int out_size, void* d_ws, size_t ws_size,
                              hipStream_t stream) {
    const float* x    = (const float*)d_in[0];
    const float* Wih0 = (const float*)d_in[1];
    const float* Whh0 = (const float*)d_in[2];
    const float* bih0 = (const float*)d_in[3];
    const float* bhh0 = (const float*)d_in[4];
    const float* Wih1 = (const float*)d_in[5];
    const float* Whh1 = (const float*)d_in[6];
    const float* bih1 = (const float*)d_in[7];
    const float* bhh1 = (const float*)d_in[8];
    const float* fcW  = (const float*)d_in[9];
    const float* fcb  = (const float*)d_in[10];
    float* out = (float*)d_out;

    lstm_feat_kernel<<<2048 / MB, 512, 0, stream>>>(
        x, Wih0, Whh0, bih0, bhh0, Wih1, Whh1, bih1, bhh1, fcW, fcb, out);
}

// Round 3
// 315.958 us; speedup vs baseline: 1.2128x; 1.1344x over previous
//
#include <hip/hip_runtime.h>
#include <hip/hip_bf16.h>

// LSTMFeatureExtractor: 2-layer LSTM (H=64, IN=1, B=2048, T=512) + FC(64->32)+ReLU
// R8 = VALU diet (resubmit: R2 bench was a GPUAcquisitionTimeout, no data).
// R7 counters: MfmaUtil halved (51->27%) but time ~flat ->
// VALU issue (~950 cy/step/SIMD, 60% busy) is the wall. Cuts:
//  (a) weights/biases pre-scaled by -log2(e) / 2log2(e) -> no per-cell scale muls
//  (b) bias folded into MFMA C operand (loop-invariant splat)
//  (c) cell math packed as float2 (v_pk_*_f32) across the lane's 2 batch rows
//  (d) k-loop unrolled x2 (compile-time LDS buffer index), x staged [qp][t][2]
//      so one ds_read_b128 feeds 2 timesteps
//  (e) s_setprio(1) around MFMA clusters (L0/L1 waves are phase-split)
// Transcendentals (10/cell, unpackable) become the cell-math floor.

#define HID 64
#define TSTEPS 512
#define MB 8
#define RS 80   // f16 row stride: 160B = 40 words = 8 mod 32 -> benign

typedef _Float16 f16x8 __attribute__((ext_vector_type(8)));
typedef float f32x4 __attribute__((ext_vector_type(4)));
typedef float f32x2 __attribute__((ext_vector_type(2)));

#define KSIG (-1.44269504089f)   // -log2(e)
#define KTANH (2.88539008178f)   // 2*log2(e)

__device__ __forceinline__ f32x2 mk2(float a, float b) { f32x2 r; r[0] = a; r[1] = b; return r; }
__device__ __forceinline__ f32x2 exp2v(f32x2 v) {
    f32x2 r; r[0] = __builtin_amdgcn_exp2f(v[0]); r[1] = __builtin_amdgcn_exp2f(v[1]); return r;
}
__device__ __forceinline__ f32x2 rcpv(f32x2 v) {
    f32x2 r; r[0] = __builtin_amdgcn_rcpf(v[0]); r[1] = __builtin_amdgcn_rcpf(v[1]); return r;
}
// inputs pre-scaled: sigmoid arg by KSIG, tanh arg by KTANH
__device__ __forceinline__ f32x2 sig2(f32x2 p)  { return rcpv(exp2v(p) + 1.0f); }
__device__ __forceinline__ f32x2 tanh2(f32x2 p) { return 1.0f - 2.0f * rcpv(exp2v(p) + 1.0f); }

__global__ __launch_bounds__(512, 1) void lstm_feat_kernel(
    const float* __restrict__ x,
    const float* __restrict__ Wih0, const float* __restrict__ Whh0,
    const float* __restrict__ bih0, const float* __restrict__ bhh0,
    const float* __restrict__ Wih1, const float* __restrict__ Whh1,
    const float* __restrict__ bih1, const float* __restrict__ bhh1,
    const float* __restrict__ fcW, const float* __restrict__ fcb,
    float* __restrict__ out)
{
    __shared__ float x_lds[(MB / 2) * TSTEPS * 2];          // [quad][t][2], 16 KB
    __shared__ __align__(16) _Float16 h0_lds[2][MB * RS];
    __shared__ __align__(16) _Float16 h1_lds[2][MB * RS];
    __shared__ float h1f32[MB * HID];
    __shared__ float fcw_lds[HID * 32];                     // transposed [k][o]
    __shared__ float fcb_lds[32];

    const int tid  = threadIdx.x;
    const int wave = tid >> 6;
    const int lane = tid & 63;
    const int nq   = lane & 15;
    const int quad = lane >> 4;
    const int bbase = blockIdx.x * MB;
    const bool isL1 = (wave >= 4);     // waves 0-3: layer0, waves 4-7: layer1
    const int ug = wave & 3;
    const int u  = ug * 16 + nq;       // hidden unit owned by this lane

    // ---- one-time staging ----
    for (int i = tid; i < TSTEPS * MB; i += 512) {
        int r = i >> 9, t = i & (TSTEPS - 1);
        // layout: [r>>1][t][r&1] -> one b128 = 2 timesteps x 2 batch rows
        x_lds[(r >> 1) * (TSTEPS * 2) + t * 2 + (r & 1)] = x[(bbase + r) * TSTEPS + t];
    }
    for (int i = tid; i < 32 * HID; i += 512) {
        int o = i >> 6, kk = i & 63;
        fcw_lds[kk * 32 + o] = fcW[i];
    }
    if (tid < 32) fcb_lds[tid] = fcb[tid];
    for (int i = tid; i < 2 * MB * RS; i += 512) {
        ((_Float16*)h0_lds)[i] = (_Float16)0.f;
        ((_Float16*)h1_lds)[i] = (_Float16)0.f;
    }

    // ---- per-lane weight fragments, PRE-SCALED by gate constant ----
    // L0 waves: wA = Whh0. L1 waves: wA = Wih1, wB = Whh1.
    f16x8 wA[4][2], wB[4][2];
    f32x4 cbias[4];                    // scaled bias splat -> MFMA C operand
    float wx0s[4];
    {
        const float* Wa = isL1 ? Wih1 : Whh0;
        const float* Wb = isL1 ? Whh1 : Whh0;
        const float* bi = isL1 ? bih1 : bih0;
        const float* bh = isL1 ? bhh1 : bhh0;
        #pragma unroll
        for (int g = 0; g < 4; ++g) {
            const float sc = (g == 2) ? KTANH : KSIG;
            const int n = g * 64 + u;
            const float bs = (bi[n] + bh[n]) * sc;
            cbias[g] = (f32x4){bs, bs, bs, bs};
            wx0s[g] = Wih0[n] * sc;    // IN==1 (L0 waves only)
            #pragma unroll
            for (int ks = 0; ks < 2; ++ks) {
                const int k0 = quad * 8 + ks * 32;
                f16x8 a, b;
                #pragma unroll
                for (int j = 0; j < 8; ++j) {
                    a[j] = (_Float16)(Wa[n * HID + k0 + j] * sc);
                    b[j] = (_Float16)(Wb[n * HID + k0 + j] * sc);
                }
                wA[g][ks] = a; wB[g][ks] = b;
            }
        }
    }

    const f32x4 zero4 = {0.f, 0.f, 0.f, 0.f};
    // A row m carries h[m>>1]; D row quad*4+reg -> batch (quad*4+reg)>>1:
    // regs {0,1}->b0 (use elem 0), {2,3}->b0+1 (use elem 2).
    const int arow = (nq >> 1) * RS + quad * 8;
    const int b0r  = (quad * 2) * RS;  // byte-row of this lane's first batch
    const int hbase = quad * 2;        // first batch row index
    f32x2 cc = mk2(0.f, 0.f);          // packed cell state (both batch rows)

    __syncthreads();

// ---- one layer-0 substep, compile-time buffers P->Q ----
#define L0_SUB(P, Q, XQ2) do {                                                       \
    f16x8 a0_ = *(const f16x8*)&h0_lds[P][arow];                                     \
    f16x8 a1_ = *(const f16x8*)&h0_lds[P][arow + 32];                                \
    f32x4 ac[4];                                                                     \
    __builtin_amdgcn_s_setprio(1);                                                   \
    _Pragma("unroll")                                                                \
    for (int g = 0; g < 4; ++g)                                                      \
        ac[g] = __builtin_amdgcn_mfma_f32_16x16x32_f16(a0_, wA[g][0], cbias[g], 0, 0, 0); \
    _Pragma("unroll")                                                                \
    for (int g = 0; g < 4; ++g)                                                      \
        ac[g] = __builtin_amdgcn_mfma_f32_16x16x32_f16(a1_, wA[g][1], ac[g], 0, 0, 0); \
    __builtin_amdgcn_s_setprio(0);                                                   \
    f32x2 pi = (XQ2) * wx0s[0] + mk2(ac[0][0], ac[0][2]);                            \
    f32x2 pf = (XQ2) * wx0s[1] + mk2(ac[1][0], ac[1][2]);                            \
    f32x2 pg = (XQ2) * wx0s[2] + mk2(ac[2][0], ac[2][2]);                            \
    f32x2 po = (XQ2) * wx0s[3] + mk2(ac[3][0], ac[3][2]);                            \
    f32x2 iv = sig2(pi), fv = sig2(pf), gv = tanh2(pg), ov = sig2(po);               \
    cc = fv * cc + iv * gv;                                                          \
    f32x2 hh = ov * tanh2(cc * KTANH);                                               \
    h0_lds[Q][b0r + u]      = (_Float16)hh[0];                                       \
    h0_lds[Q][b0r + RS + u] = (_Float16)hh[1];                                       \
} while (0)

// ---- one layer-1 substep; GUARD=false suppresses the k==0 commit ----
#define L1_SUB(P, Q, GUARD) do {                                                     \
    f16x8 a00 = *(const f16x8*)&h0_lds[P][arow];                                     \
    f16x8 a01 = *(const f16x8*)&h0_lds[P][arow + 32];                                \
    f16x8 a10 = *(const f16x8*)&h1_lds[P][arow];                                     \
    f16x8 a11 = *(const f16x8*)&h1_lds[P][arow + 32];                                \
    f32x4 aA[4], aB[4];                                                              \
    __builtin_amdgcn_s_setprio(1);                                                   \
    _Pragma("unroll")                                                                \
    for (int g = 0; g < 4; ++g)                                                      \
        aA[g] = __builtin_amdgcn_mfma_f32_16x16x32_f16(a00, wA[g][0], zero4, 0, 0, 0); \
    _Pragma("unroll")                                                                \
    for (int g = 0; g < 4; ++g)                                                      \
        aB[g] = __builtin_amdgcn_mfma_f32_16x16x32_f16(a10, wB[g][0], cbias[g], 0, 0, 0); \
    _Pragma("unroll")                                                                \
    for (int g = 0; g < 4; ++g)                                                      \
        aA[g] = __builtin_amdgcn_mfma_f32_16x16x32_f16(a01, wA[g][1], aA[g], 0, 0, 0); \
    _Pragma("unroll")                                                                \
    for (int g = 0; g < 4; ++g)                                                      \
        aB[g] = __builtin_amdgcn_mfma_f32_16x16x32_f16(a11, wB[g][1], aB[g], 0, 0, 0); \
    __builtin_amdgcn_s_setprio(0);                                                   \
    if (GUARD) {                                                                     \
        f32x2 pi = mk2(aA[0][0], aA[0][2]) + mk2(aB[0][0], aB[0][2]);                \
        f32x2 pf = mk2(aA[1][0], aA[1][2]) + mk2(aB[1][0], aB[1][2]);                \
        f32x2 pg = mk2(aA[2][0], aA[2][2]) + mk2(aB[2][0], aB[2][2]);                \
        f32x2 po = mk2(aA[3][0], aA[3][2]) + mk2(aB[3][0], aB[3][2]);                \
        f32x2 iv = sig2(pi), fv = sig2(pf), gv = tanh2(pg), ov = sig2(po);           \
        cc = fv * cc + iv * gv;                                                      \
        f32x2 hh = ov * tanh2(cc * KTANH);                                           \
        h1_lds[Q][b0r + u]      = (_Float16)hh[0];                                   \
        h1_lds[Q][b0r + RS + u] = (_Float16)hh[1];                                   \
    }                                                                                \
} while (0)

    // ---- skewed recurrence, unrolled x2 (buffers 0->1 then 1->0) ----
    const int xoff = quad * (TSTEPS * 2);
    for (int k = 0; k < TSTEPS; k += 2) {
        f32x2 xa, xb;
        if (!isL1) {
            const f32x4 xv = *(const f32x4*)&x_lds[xoff + k * 2];
            xa = mk2(xv[0], xv[1]); xb = mk2(xv[2], xv[3]);
            L0_SUB(0, 1, xa);
        } else {
            L1_SUB(0, 1, (k > 0));
        }
        __syncthreads();
        if (!isL1) {
            L0_SUB(1, 0, xb);
        } else {
            L1_SUB(1, 0, true);
        }
        __syncthreads();
    }

    // ---- peeled final layer-1 step: H1[512] from H0[512] (buf 0), H1[511] ----
    if (isL1) {
        f16x8 a00 = *(const f16x8*)&h0_lds[0][arow];
        f16x8 a01 = *(const f16x8*)&h0_lds[0][arow + 32];
        f16x8 a10 = *(const f16x8*)&h1_lds[0][arow];
        f16x8 a11 = *(const f16x8*)&h1_lds[0][arow + 32];
        f32x4 aA[4], aB[4];
        #pragma unroll
        for (int g = 0; g < 4; ++g)
            aA[g] = __builtin_amdgcn_mfma_f32_16x16x32_f16(a00, wA[g][0], zero4, 0, 0, 0);
        #pragma unroll
        for (int g = 0; g < 4; ++g)
            aB[g] = __builtin_amdgcn_mfma_f32_16x16x32_f16(a10, wB[g][0], cbias[g], 0, 0, 0);
        #pragma unroll
        for (int g = 0; g < 4; ++g)
            aA[g] = __builtin_amdgcn_mfma_f32_16x16x32_f16(a01, wA[g][1], aA[g], 0, 0, 0);
        #pragma unroll
        for (int g = 0; g < 4; ++g)
            aB[g] = __builtin_amdgcn_mfma_f32_16x16x32_f16(a11, wB[g][1], aB[g], 0, 0, 0);
        f32x2 pi = mk2(aA[0][0], aA[0][2]) + mk2(aB[0][0], aB[0][2]);
        f32x2 pf = mk2(aA[1][0], aA[1][2]) + mk2(aB[1][0], aB[1][2]);
        f32x2 pg = mk2(aA[2][0], aA[2][2]) + mk2(aB[2][0], aB[2][2]);
        f32x2 po = mk2(aA[3][0], aA[3][2]) + mk2(aB[3][0], aB[3][2]);
        f32x2 iv = sig2(pi), fv = sig2(pf), gv = tanh2(pg), ov = sig2(po);
        cc = fv * cc + iv * gv;
        f32x2 hh = ov * tanh2(cc * KTANH);
        h1f32[hbase * HID + u]       = hh[0];
        h1f32[(hbase + 1) * HID + u] = hh[1];
    }
    __syncthreads();

    // ---- epilogue: features = relu(H1[512] @ fcW^T + fcb) ----
    if (tid < MB * 32) {
        const int o  = tid & 31;
        const int rr = tid >> 5;
        float acc = fcb_lds[o];
        #pragma unroll 8
        for (int kk = 0; kk < HID; ++kk)
            acc += h1f32[rr * HID + kk] * fcw_lds[kk * 32 + o];
        out[(bbase + rr) * 32 + o] = fmaxf(acc, 0.f);
    }
}

extern "C" void kernel_launch(void* const* d_in, const int* in_sizes, int n_in,
                              void* d_out, int out_size, void* d_ws, size_t ws_size,
                              hipStream_t stream) {
    const float* x    = (const float*)d_in[0];
    const float* Wih0 = (const float*)d_in[1];
    const float* Whh0 = (const float*)d_in[2];
    const float* bih0 = (const float*)d_in[3];
    const float* bhh0 = (const float*)d_in[4];
    const float* Wih1 = (const float*)d_in[5];
    const float* Whh1 = (const float*)d_in[6];
    const float* bih1 = (const float*)d_in[7];
    const float* bhh1 = (const float*)d_in[8];
    const float* fcW  = (const float*)d_in[9];
    const float* fcb  = (const float*)d_in[10];
    float* out = (float*)d_out;

    lstm_feat_kernel<<<2048 / MB, 512, 0, stream>>>(
        x, Wih0, Whh0, bih0, bhh0, Wih1, Whh1, bih1, bhh1, fcW, fcb, out);
}

// Round 4
// 312.710 us; speedup vs baseline: 1.2254x; 1.0104x over previous
//
#include <hip/hip_runtime.h>
#include <hip/hip_bf16.h>

// LSTMFeatureExtractor: 2-layer LSTM (H=64, IN=1, B=2048, T=512) + FC(64->32)+ReLU
// R9 = break the barrier phase-lock. R8 counters: step=1331cy with MFMA 418 +
// VALU 646 + stall 270 running SERIALLY (both waves/SIMD hit identical stall
// points). Changes:
//  (1) 2-deep h0->L1 skew + 4-buffer H0 ring: L1's accA (Wih1*h0+bias) is
//      prefetched one interval early into regs; on-path L1 = 8 accB MFMAs
//      chained onto accA (C operand). No pre-act adds/extracts.
//  (2) L0 folds bias + x*Wih0 into the MFMA C operand (built pre-MFMA).
//  (3) scalar cell math straight off acc[g][0]/acc[g][2] (no pk pack movs).
// Expect L1-prefetch MFMAs to overlap L0 trans chains across waves.

#define HID 64
#define TSTEPS 512
#define MB 8
#define RS 80   // f16 row stride: 160B

typedef _Float16 f16x8 __attribute__((ext_vector_type(8)));
typedef float f32x4 __attribute__((ext_vector_type(4)));

#define KSIG (-1.44269504089f)   // -log2(e)
#define KTANH (2.88539008178f)   // 2*log2(e)

__device__ __forceinline__ float sig1(float p) {   // p pre-scaled by KSIG
    return __builtin_amdgcn_rcpf(1.f + __builtin_amdgcn_exp2f(p));
}
__device__ __forceinline__ float th1(float p) {    // p pre-scaled by KTANH
    return 1.f - 2.f * __builtin_amdgcn_rcpf(1.f + __builtin_amdgcn_exp2f(p));
}

__global__ __launch_bounds__(512, 1) void lstm_feat_kernel(
    const float* __restrict__ x,
    const float* __restrict__ Wih0, const float* __restrict__ Whh0,
    const float* __restrict__ bih0, const float* __restrict__ bhh0,
    const float* __restrict__ Wih1, const float* __restrict__ Whh1,
    const float* __restrict__ bih1, const float* __restrict__ bhh1,
    const float* __restrict__ fcW, const float* __restrict__ fcb,
    float* __restrict__ out)
{
    __shared__ float x_lds[(MB / 2) * TSTEPS * 2];          // [quad][t][2], 16 KB
    __shared__ __align__(16) _Float16 h0_lds[4][MB * RS];   // H0[t] in buf t&3
    __shared__ __align__(16) _Float16 h1_lds[2][MB * RS];   // H1[s] in buf s&1
    __shared__ float h1f32[MB * HID];
    __shared__ float fcw_lds[HID * 32];                     // transposed [k][o]
    __shared__ float fcb_lds[32];

    const int tid  = threadIdx.x;
    const int wave = tid >> 6;
    const int lane = tid & 63;
    const int nq   = lane & 15;
    const int quad = lane >> 4;
    const int bbase = blockIdx.x * MB;
    const bool isL1 = (wave >= 4);     // waves 0-3: layer0, waves 4-7: layer1
    const int ug = wave & 3;
    const int u  = ug * 16 + nq;       // hidden unit owned by this lane

    // ---- one-time staging ----
    for (int i = tid; i < TSTEPS * MB; i += 512) {
        int r = i >> 9, t = i & (TSTEPS - 1);
        x_lds[(r >> 1) * (TSTEPS * 2) + t * 2 + (r & 1)] = x[(bbase + r) * TSTEPS + t];
    }
    for (int i = tid; i < 32 * HID; i += 512) {
        int o = i >> 6, kk = i & 63;
        fcw_lds[kk * 32 + o] = fcW[i];
    }
    if (tid < 32) fcb_lds[tid] = fcb[tid];
    for (int i = tid; i < 4 * MB * RS; i += 512) ((_Float16*)h0_lds)[i] = (_Float16)0.f;
    for (int i = tid; i < 2 * MB * RS; i += 512) ((_Float16*)h1_lds)[i] = (_Float16)0.f;

    // ---- per-lane weight fragments, PRE-SCALED by gate constant ----
    // L0 waves: wA = Whh0. L1 waves: wA = Wih1, wB = Whh1.
    f16x8 wA[4][2], wB[4][2];
    f32x4 cbias[4];
    float bsc[4], wx0s[4];
    {
        const float* Wa = isL1 ? Wih1 : Whh0;
        const float* Wb = isL1 ? Whh1 : Whh0;
        const float* bi = isL1 ? bih1 : bih0;
        const float* bh = isL1 ? bhh1 : bhh0;
        #pragma unroll
        for (int g = 0; g < 4; ++g) {
            const float sc = (g == 2) ? KTANH : KSIG;
            const int n = g * 64 + u;
            const float bs = (bi[n] + bh[n]) * sc;
            bsc[g] = bs;
            cbias[g] = (f32x4){bs, bs, bs, bs};
            wx0s[g] = Wih0[n] * sc;    // IN==1 (L0 waves only)
            #pragma unroll
            for (int ks = 0; ks < 2; ++ks) {
                const int k0 = quad * 8 + ks * 32;
                f16x8 a, b;
                #pragma unroll
                for (int j = 0; j < 8; ++j) {
                    a[j] = (_Float16)(Wa[n * HID + k0 + j] * sc);
                    b[j] = (_Float16)(Wb[n * HID + k0 + j] * sc);
                }
                wA[g][ks] = a; wB[g][ks] = b;
            }
        }
    }

    // A row m carries h[m>>1]; D row quad*4+reg -> batch (quad*4+reg)>>1:
    // regs {0,1}->b0 (elem 0), {2,3}->b0+1 (elem 2).
    const int arow = (nq >> 1) * RS + quad * 8;
    const int b0r  = (quad * 2) * RS;
    const int hbase = quad * 2;
    float c0 = 0.f, c1 = 0.f;
    f32x4 accA[4] = { {0,0,0,0},{0,0,0,0},{0,0,0,0},{0,0,0,0} };

    __syncthreads();

// ---- scalar cell math: pre-acts straight from acc elems 0/2 ----
#define CELL(AC, DST) do {                                                        \
    float i0 = sig1(AC[0][0]), i1 = sig1(AC[0][2]);                               \
    float f0 = sig1(AC[1][0]), f1 = sig1(AC[1][2]);                               \
    float g0 = th1(AC[2][0]),  g1 = th1(AC[2][2]);                                \
    float o0 = sig1(AC[3][0]), o1 = sig1(AC[3][2]);                               \
    c0 = f0 * c0 + i0 * g0;  c1 = f1 * c1 + i1 * g1;                              \
    float t0 = th1(c0 * KTANH), t1 = th1(c1 * KTANH);                             \
    (DST)[b0r + u]      = (_Float16)(o0 * t0);                                    \
    (DST)[b0r + RS + u] = (_Float16)(o1 * t1);                                    \
} while (0)

// ---- L0 interval j: H0[j] (buf P) + x[j] -> H0[j+1] (buf Q) ----
#define L0_STEP(P, Q, XA, XB) do {                                                \
    f16x8 a0 = *(const f16x8*)&h0_lds[P][arow];                                   \
    f16x8 a1 = *(const f16x8*)&h0_lds[P][arow + 32];                              \
    f32x4 ac[4];                                                                  \
    __builtin_amdgcn_s_setprio(1);                                                \
    _Pragma("unroll")                                                             \
    for (int g = 0; g < 4; ++g) {                                                 \
        f32x4 Cg;                                                                 \
        Cg[0] = fmaf((XA), wx0s[g], bsc[g]); Cg[1] = bsc[g];                      \
        Cg[2] = fmaf((XB), wx0s[g], bsc[g]); Cg[3] = bsc[g];                      \
        ac[g] = __builtin_amdgcn_mfma_f32_16x16x32_f16(a0, wA[g][0], Cg, 0, 0, 0);\
    }                                                                             \
    _Pragma("unroll")                                                             \
    for (int g = 0; g < 4; ++g)                                                   \
        ac[g] = __builtin_amdgcn_mfma_f32_16x16x32_f16(a1, wA[g][1], ac[g], 0, 0, 0); \
    __builtin_amdgcn_s_setprio(0);                                                \
    CELL(ac, h0_lds[Q]);                                                          \
} while (0)

// ---- L1 interval j (s=j-1): accB over H1[s-1] (h1 buf RB) chained onto
//      prefetched accA; cell -> H1[s] (h1 buf WRB); prefetch accA from
//      H0[j] (h0 buf PF) for interval j+1 ----
#define L1_STEP(RB, WRB, PF) do {                                                 \
    f16x8 b0v = *(const f16x8*)&h1_lds[RB][arow];                                 \
    f16x8 b1v = *(const f16x8*)&h1_lds[RB][arow + 32];                            \
    f16x8 p0 = *(const f16x8*)&h0_lds[PF][arow];                                  \
    f16x8 p1 = *(const f16x8*)&h0_lds[PF][arow + 32];                             \
    f32x4 ac[4];                                                                  \
    __builtin_amdgcn_s_setprio(1);                                                \
    _Pragma("unroll")                                                             \
    for (int g = 0; g < 4; ++g)                                                   \
        ac[g] = __builtin_amdgcn_mfma_f32_16x16x32_f16(b0v, wB[g][0], accA[g], 0, 0, 0); \
    _Pragma("unroll")                                                             \
    for (int g = 0; g < 4; ++g)                                                   \
        ac[g] = __builtin_amdgcn_mfma_f32_16x16x32_f16(b1v, wB[g][1], ac[g], 0, 0, 0);   \
    __builtin_amdgcn_s_setprio(0);                                                \
    _Pragma("unroll")                                                             \
    for (int g = 0; g < 4; ++g)                                                   \
        accA[g] = __builtin_amdgcn_mfma_f32_16x16x32_f16(p0, wA[g][0], cbias[g], 0, 0, 0); \
    _Pragma("unroll")                                                             \
    for (int g = 0; g < 4; ++g)                                                   \
        accA[g] = __builtin_amdgcn_mfma_f32_16x16x32_f16(p1, wA[g][1], accA[g], 0, 0, 0);  \
    CELL(ac, h1_lds[WRB]);                                                        \
} while (0)

// ---- L1 prefetch-only (prologue intervals where s<1) ----
#define L1_PF(PF) do {                                                            \
    f16x8 p0 = *(const f16x8*)&h0_lds[PF][arow];                                  \
    f16x8 p1 = *(const f16x8*)&h0_lds[PF][arow + 32];                             \
    _Pragma("unroll")                                                             \
    for (int g = 0; g < 4; ++g)                                                   \
        accA[g] = __builtin_amdgcn_mfma_f32_16x16x32_f16(p0, wA[g][0], cbias[g], 0, 0, 0); \
    _Pragma("unroll")                                                             \
    for (int g = 0; g < 4; ++g)                                                   \
        accA[g] = __builtin_amdgcn_mfma_f32_16x16x32_f16(p1, wA[g][1], accA[g], 0, 0, 0);  \
} while (0)

    const int xoff = quad * (TSTEPS * 2);

    // ---- prologue intervals j=0..3 (L1 guards compile-time) ----
    {
        const f32x4 xv0 = *(const f32x4*)&x_lds[xoff + 0];
        const f32x4 xv1 = *(const f32x4*)&x_lds[xoff + 4];
        if (!isL1) L0_STEP(0, 1, xv0[0], xv0[1]); else L1_PF(0);
        __syncthreads();
        if (!isL1) L0_STEP(1, 2, xv0[2], xv0[3]); else L1_PF(1);
        __syncthreads();
        if (!isL1) L0_STEP(2, 3, xv1[0], xv1[1]); else L1_STEP(0, 1, 2);
        __syncthreads();
        if (!isL1) L0_STEP(3, 0, xv1[2], xv1[3]); else L1_STEP(1, 0, 3);
        __syncthreads();
    }

    // ---- main loop: intervals j=k..k+3 ----
    for (int k = 4; k < TSTEPS; k += 4) {
        const f32x4 xv0 = *(const f32x4*)&x_lds[xoff + k * 2];
        const f32x4 xv1 = *(const f32x4*)&x_lds[xoff + k * 2 + 4];
        if (!isL1) L0_STEP(0, 1, xv0[0], xv0[1]); else L1_STEP(0, 1, 0);
        __syncthreads();
        if (!isL1) L0_STEP(1, 2, xv0[2], xv0[3]); else L1_STEP(1, 0, 1);
        __syncthreads();
        if (!isL1) L0_STEP(2, 3, xv1[0], xv1[1]); else L1_STEP(0, 1, 2);
        __syncthreads();
        if (!isL1) L0_STEP(3, 0, xv1[2], xv1[3]); else L1_STEP(1, 0, 3);
        __syncthreads();
    }

    // ---- peeled s=511: accA holds Wih1*H0[511]+b; state H1[510] in buf 0 ----
    if (isL1) {
        f16x8 b0v = *(const f16x8*)&h1_lds[0][arow];
        f16x8 b1v = *(const f16x8*)&h1_lds[0][arow + 32];
        f32x4 ac[4];
        #pragma unroll
        for (int g = 0; g < 4; ++g)
            ac[g] = __builtin_amdgcn_mfma_f32_16x16x32_f16(b0v, wB[g][0], accA[g], 0, 0, 0);
        #pragma unroll
        for (int g = 0; g < 4; ++g)
            ac[g] = __builtin_amdgcn_mfma_f32_16x16x32_f16(b1v, wB[g][1], ac[g], 0, 0, 0);
        CELL(ac, h1_lds[1]);
    }
    __syncthreads();

    // ---- peeled s=512: H0[512] in h0 buf 0, H1[511] in h1 buf 1 ----
    if (isL1) {
        f16x8 p0  = *(const f16x8*)&h0_lds[0][arow];
        f16x8 p1  = *(const f16x8*)&h0_lds[0][arow + 32];
        f16x8 b0v = *(const f16x8*)&h1_lds[1][arow];
        f16x8 b1v = *(const f16x8*)&h1_lds[1][arow + 32];
        f32x4 ac[4];
        #pragma unroll
        for (int g = 0; g < 4; ++g)
            ac[g] = __builtin_amdgcn_mfma_f32_16x16x32_f16(p0, wA[g][0], cbias[g], 0, 0, 0);
        #pragma unroll
        for (int g = 0; g < 4; ++g)
            ac[g] = __builtin_amdgcn_mfma_f32_16x16x32_f16(p1, wA[g][1], ac[g], 0, 0, 0);
        #pragma unroll
        for (int g = 0; g < 4; ++g)
            ac[g] = __builtin_amdgcn_mfma_f32_16x16x32_f16(b0v, wB[g][0], ac[g], 0, 0, 0);
        #pragma unroll
        for (int g = 0; g < 4; ++g)
            ac[g] = __builtin_amdgcn_mfma_f32_16x16x32_f16(b1v, wB[g][1], ac[g], 0, 0, 0);
        float i0 = sig1(ac[0][0]), i1 = sig1(ac[0][2]);
        float f0 = sig1(ac[1][0]), f1 = sig1(ac[1][2]);
        float g0 = th1(ac[2][0]),  g1 = th1(ac[2][2]);
        float o0 = sig1(ac[3][0]), o1 = sig1(ac[3][2]);
        c0 = f0 * c0 + i0 * g0;  c1 = f1 * c1 + i1 * g1;
        h1f32[hbase * HID + u]       = o0 * th1(c0 * KTANH);
        h1f32[(hbase + 1) * HID + u] = o1 * th1(c1 * KTANH);
    }
    __syncthreads();

    // ---- epilogue: features = relu(H1[512] @ fcW^T + fcb) ----
    if (tid < MB * 32) {
        const int o  = tid & 31;
        const int rr = tid >> 5;
        float acc = fcb_lds[o];
        #pragma unroll 8
        for (int kk = 0; kk < HID; ++kk)
            acc += h1f32[rr * HID + kk] * fcw_lds[kk * 32 + o];
        out[(bbase + rr) * 32 + o] = fmaxf(acc, 0.f);
    }
}

extern "C" void kernel_launch(void* const* d_in, const int* in_sizes, int n_in,
                              void* d_out, int out_size, void* d_ws, size_t ws_size,
                              hipStream_t stream) {
    const float* x    = (const float*)d_in[0];
    const float* Wih0 = (const float*)d_in[1];
    const float* Whh0 = (const float*)d_in[2];
    const float* bih0 = (const float*)d_in[3];
    const float* bhh0 = (const float*)d_in[4];
    const float* Wih1 = (const float*)d_in[5];
    const float* Whh1 = (const float*)d_in[6];
    const float* bih1 = (const float*)d_in[7];
    const float* bhh1 = (const float*)d_in[8];
    const float* fcW  = (const float*)d_in[9];
    const float* fcb  = (const float*)d_in[10];
    float* out = (float*)d_out;

    lstm_feat_kernel<<<2048 / MB, 512, 0, stream>>>(
        x, Wih0, Whh0, bih0, bhh0, Wih1, Whh1, bih1, bhh1, fcW, fcb, out);
}